// Round 7
// baseline (42.827 us; speedup 1.0000x reference)
//
#include <hip/hip_runtime.h>

#define HW 512
#define PSTRIDE 66    // shorts per patch slot in pbuf (33 dwords -> odd bank step)
#define BSTRIDE 266   // shorts per batch in pbuf (133 dwords -> odd bank step)

typedef __attribute__((ext_vector_type(4))) float f32x4;
typedef __attribute__((ext_vector_type(4))) int   i32x4;
typedef __attribute__((ext_vector_type(8))) short b16x8;
typedef __attribute__((ext_vector_type(4))) short b16x4;

__device__ __forceinline__ short f2bf(float f) {
    union { float f; unsigned u; } v; v.f = f;
    return (short)((v.u + 0x7FFFu + ((v.u >> 16) & 1u)) >> 16);  // RNE
}

__global__ __launch_bounds__(256, 8) void axonal_kernel(
    const float* __restrict__ src, const float* __restrict__ tr,
    const float* __restrict__ gates, const float* __restrict__ biases,
    float* __restrict__ out)
{
    // bh in bit 3: the two blocks sharing a patch-quad's transforms (bid, bid^8)
    // land on the same XCD -> their concurrent tr reads merge in that L2.
    const int bid = blockIdx.x;                    // 0..2047
    const int bh  = (bid >> 3) & 1;                // batch half
    const int q   = (bid >> 4) * 8 + (bid & 7);    // patch-quad 0..1023
    const int ph  = q >> 4;
    const int pq  = q & 15;                        // 4 adjacent pw = 128B line
    const int tid = threadIdx.x;
    const int w   = tid >> 6;                      // wave = patch within quad
    const int lane = tid & 63;
    const int lo  = lane & 15;
    const int hi  = lane >> 4;
    const int p   = (ph << 6) + (pq << 2) + w;

    __shared__ __align__(16) short pbuf[32 * BSTRIDE];  // [32 b][4 p][64+pad] bf16
    __shared__ float smask[4 * 32];                     // [patch][batch] strength

    // ---- B fragments (Tr[p]^T) into VGPRs, once.
    // mfma_f32_16x16x32_bf16: elems 0-3 <- k = ks*32 + 4*hi + j, elems 4-7 <- +16; col = lane&15.
    b16x8 bfr[8];  // [n*2 + ks]
    {
        const float* tp = tr + ((size_t)p << 12);
        #pragma unroll
        for (int n = 0; n < 4; ++n)
            #pragma unroll
            for (int ks = 0; ks < 2; ++ks) {
                const float* rp = tp + (n * 16 + lo) * 64 + ks * 32 + 4 * hi;
                float4 u0 = *reinterpret_cast<const float4*>(rp);
                float4 u1 = *reinterpret_cast<const float4*>(rp + 16);
                b16x8 v;
                v[0] = f2bf(u0.x); v[1] = f2bf(u0.y); v[2] = f2bf(u0.z); v[3] = f2bf(u0.w);
                v[4] = f2bf(u1.x); v[5] = f2bf(u1.y); v[6] = f2bf(u1.z); v[7] = f2bf(u1.w);
                bfr[n * 2 + ks] = v;
            }
    }
    // Pin fragments so the tr loads can't be re-sunk past the barrier (round-5 failure).
    #pragma unroll
    for (int i = 0; i < 8; ++i) {
        i32x4 kv = (i32x4)bfr[i];
        asm volatile("" :: "v"(kv));
    }
    const float g  = gates[p];
    const float bi = biases[p];

    // ---- stage 32 batches: thread = (batch sb, col-quad u); 8 rows each.
    // Per wave-instr: 8 batches x 128B contiguous segments.
    {
        const int sb = tid >> 3;        // 0..31
        const int u  = tid & 7;         // col-quad; patch = u>>1
        const float* sp = src + (size_t)(bh * 32 + sb) * HW * HW
                              + (size_t)(ph * 8) * HW + pq * 32 + u * 4;
        short* dst = &pbuf[sb * BSTRIDE + (u >> 1) * PSTRIDE + (u & 1) * 4];
        float ssum = 0.f;
        #pragma unroll
        for (int r = 0; r < 8; ++r) {
            float4 v = *reinterpret_cast<const float4*>(sp + r * HW);
            ssum += (v.x + v.y) + (v.z + v.w);
            b16x4 bv;
            bv[0] = f2bf(v.x); bv[1] = f2bf(v.y); bv[2] = f2bf(v.z); bv[3] = f2bf(v.w);
            *reinterpret_cast<b16x4*>(dst + r * 8) = bv;
        }
        ssum += __shfl_xor(ssum, 1);    // partner col-quad of same patch
        if ((u & 1) == 0) smask[(u >> 1) * 32 + sb] = ssum;
    }
    __syncthreads();   // the only barrier

    // ---- 2 batch-groups of 16; per group: 4 ds_read_b64 + 8 MFMAs, direct stores.
    #pragma unroll
    for (int bg = 0; bg < 2; ++bg) {
        f32x4 acc0 = (f32x4){0.f, 0.f, 0.f, 0.f};
        f32x4 acc1 = acc0, acc2 = acc0, acc3 = acc0;
        #pragma unroll
        for (int ks = 0; ks < 2; ++ks) {
            const short* ap = &pbuf[(bg * 16 + lo) * BSTRIDE + w * PSTRIDE + ks * 32 + 4 * hi];
            b16x4 a0 = *reinterpret_cast<const b16x4*>(ap);
            b16x4 a1 = *reinterpret_cast<const b16x4*>(ap + 16);
            b16x8 a;
            a[0] = a0[0]; a[1] = a0[1]; a[2] = a0[2]; a[3] = a0[3];
            a[4] = a1[0]; a[5] = a1[1]; a[6] = a1[2]; a[7] = a1[3];
            acc0 = __builtin_amdgcn_mfma_f32_16x16x32_bf16(a, bfr[0 + ks], acc0, 0, 0, 0);
            acc1 = __builtin_amdgcn_mfma_f32_16x16x32_bf16(a, bfr[2 + ks], acc1, 0, 0, 0);
            acc2 = __builtin_amdgcn_mfma_f32_16x16x32_bf16(a, bfr[4 + ks], acc2, 0, 0, 0);
            acc3 = __builtin_amdgcn_mfma_f32_16x16x32_bf16(a, bfr[6 + ks], acc3, 0, 0, 0);
        }

        // C/D: col(t-part)=lane&15, row(batch-in-group)=4*hi+reg. Direct stores;
        // the block's 4 waves cover a full 128B line per (batch,row) -> L2 merges.
        f32x4 mk = *reinterpret_cast<const f32x4*>(&smask[w * 32 + bg * 16 + 4 * hi]);
        float* ob = out + (size_t)(bh * 32 + bg * 16 + 4 * hi) * HW * HW
                        + (size_t)(ph * 8 + (lo >> 3)) * HW + pq * 32 + w * 8 + (lo & 7);
        #pragma unroll
        for (int n = 0; n < 4; ++n) {
            f32x4 acc = (n == 0) ? acc0 : (n == 1) ? acc1 : (n == 2) ? acc2 : acc3;
            #pragma unroll
            for (int q2 = 0; q2 < 4; ++q2) {
                float val = fmaf(acc[q2], g, bi);
                val = (mk[q2] > 0.f) ? val : 0.f;
                ob[(size_t)q2 * HW * HW + (size_t)(2 * n) * HW] = val;
            }
        }
    }
}

extern "C" void kernel_launch(void* const* d_in, const int* in_sizes, int n_in,
                              void* d_out, int out_size, void* d_ws, size_t ws_size,
                              hipStream_t stream) {
    const float* src    = (const float*)d_in[0];
    const float* tr     = (const float*)d_in[1];
    const float* gates  = (const float*)d_in[2];
    const float* biases = (const float*)d_in[3];
    float* out = (float*)d_out;

    dim3 grid(2048);   // exactly 8 blocks/CU x 256 CUs, zero tail
    dim3 block(256);   // 4 waves, wave = patch
    hipLaunchKernelGGL(axonal_kernel, grid, block, 0, stream,
                       src, tr, gates, biases, out);
}

// Round 8
// 40.547 us; speedup vs baseline: 1.0562x; 1.0562x over previous
//
#include <hip/hip_runtime.h>

#define HW 512
#define PSTRIDE 66    // shorts per patch slot in pbuf (33 dwords -> odd bank step)
#define BSTRIDE 266   // shorts per batch in pbuf (133 dwords -> odd bank step)

typedef __attribute__((ext_vector_type(4))) float f32x4;
typedef __attribute__((ext_vector_type(4))) int   i32x4;
typedef __attribute__((ext_vector_type(8))) short b16x8;
typedef __attribute__((ext_vector_type(4))) short b16x4;

__device__ __forceinline__ short f2bf(float f) {
    union { float f; unsigned u; } v; v.f = f;
    return (short)((v.u + 0x7FFFu + ((v.u >> 16) & 1u)) >> 16);  // RNE
}

// (256,4): 128-VGPR budget so the B-fragments stay RESIDENT (round 6: VGPR=60).
// Actual use ~60 VGPR -> HW can still co-schedule 8 waves/SIMD; LDS 17.9KB -> 8 blocks/CU.
// (256,8) forced a 64-reg budget -> compiler rematerialized tr loads per bg group (round 7: VGPR=32).
__global__ __launch_bounds__(256, 4) void axonal_kernel(
    const float* __restrict__ src, const float* __restrict__ tr,
    const float* __restrict__ gates, const float* __restrict__ biases,
    float* __restrict__ out)
{
    // bh in bit 3: the two blocks sharing a patch-quad's transforms (bid, bid^8)
    // land on the same XCD -> their concurrent tr reads merge in that L2.
    const int bid = blockIdx.x;                    // 0..2047
    const int bh  = (bid >> 3) & 1;                // batch half
    const int q   = (bid >> 4) * 8 + (bid & 7);    // patch-quad 0..1023
    const int ph  = q >> 4;
    const int pq  = q & 15;                        // 4 adjacent pw = 128B line
    const int tid = threadIdx.x;
    const int w   = tid >> 6;                      // wave = patch within quad
    const int lane = tid & 63;
    const int lo  = lane & 15;
    const int hi  = lane >> 4;
    const int p   = (ph << 6) + (pq << 2) + w;

    __shared__ __align__(16) short pbuf[32 * BSTRIDE];  // [32 b][4 p][64+pad] bf16
    __shared__ float smask[4 * 32];                     // [patch][batch] strength

    // ---- B fragments (Tr[p]^T) into VGPRs, once.
    // mfma_f32_16x16x32_bf16: elems 0-3 <- k = ks*32 + 4*hi + j, elems 4-7 <- +16; col = lane&15.
    b16x8 bfr[8];  // [n*2 + ks]
    {
        const float* tp = tr + ((size_t)p << 12);
        #pragma unroll
        for (int n = 0; n < 4; ++n)
            #pragma unroll
            for (int ks = 0; ks < 2; ++ks) {
                const float* rp = tp + (n * 16 + lo) * 64 + ks * 32 + 4 * hi;
                float4 u0 = *reinterpret_cast<const float4*>(rp);
                float4 u1 = *reinterpret_cast<const float4*>(rp + 16);
                b16x8 v;
                v[0] = f2bf(u0.x); v[1] = f2bf(u0.y); v[2] = f2bf(u0.z); v[3] = f2bf(u0.w);
                v[4] = f2bf(u1.x); v[5] = f2bf(u1.y); v[6] = f2bf(u1.z); v[7] = f2bf(u1.w);
                bfr[n * 2 + ks] = v;
            }
    }
    // Pin fragments so the tr loads can't be re-sunk past the barrier (round-5 failure).
    #pragma unroll
    for (int i = 0; i < 8; ++i) {
        i32x4 kv = (i32x4)bfr[i];
        asm volatile("" :: "v"(kv));
    }
    const float g  = gates[p];
    const float bi = biases[p];

    // ---- stage 32 batches: thread = (batch sb, col-quad u); 8 rows each.
    // Per wave-instr: 8 batches x 128B contiguous segments.
    {
        const int sb = tid >> 3;        // 0..31
        const int u  = tid & 7;         // col-quad; patch = u>>1
        const float* sp = src + (size_t)(bh * 32 + sb) * HW * HW
                              + (size_t)(ph * 8) * HW + pq * 32 + u * 4;
        short* dst = &pbuf[sb * BSTRIDE + (u >> 1) * PSTRIDE + (u & 1) * 4];
        float ssum = 0.f;
        #pragma unroll
        for (int r = 0; r < 8; ++r) {
            float4 v = *reinterpret_cast<const float4*>(sp + r * HW);
            ssum += (v.x + v.y) + (v.z + v.w);
            b16x4 bv;
            bv[0] = f2bf(v.x); bv[1] = f2bf(v.y); bv[2] = f2bf(v.z); bv[3] = f2bf(v.w);
            *reinterpret_cast<b16x4*>(dst + r * 8) = bv;
        }
        ssum += __shfl_xor(ssum, 1);    // partner col-quad of same patch
        if ((u & 1) == 0) smask[(u >> 1) * 32 + sb] = ssum;
    }
    __syncthreads();   // the only barrier

    // ---- 2 batch-groups of 16; per group: 4 ds_read_b64 + 8 MFMAs, direct stores.
    #pragma unroll
    for (int bg = 0; bg < 2; ++bg) {
        f32x4 acc0 = (f32x4){0.f, 0.f, 0.f, 0.f};
        f32x4 acc1 = acc0, acc2 = acc0, acc3 = acc0;
        #pragma unroll
        for (int ks = 0; ks < 2; ++ks) {
            const short* ap = &pbuf[(bg * 16 + lo) * BSTRIDE + w * PSTRIDE + ks * 32 + 4 * hi];
            b16x4 a0 = *reinterpret_cast<const b16x4*>(ap);
            b16x4 a1 = *reinterpret_cast<const b16x4*>(ap + 16);
            b16x8 a;
            a[0] = a0[0]; a[1] = a0[1]; a[2] = a0[2]; a[3] = a0[3];
            a[4] = a1[0]; a[5] = a1[1]; a[6] = a1[2]; a[7] = a1[3];
            acc0 = __builtin_amdgcn_mfma_f32_16x16x32_bf16(a, bfr[0 + ks], acc0, 0, 0, 0);
            acc1 = __builtin_amdgcn_mfma_f32_16x16x32_bf16(a, bfr[2 + ks], acc1, 0, 0, 0);
            acc2 = __builtin_amdgcn_mfma_f32_16x16x32_bf16(a, bfr[4 + ks], acc2, 0, 0, 0);
            acc3 = __builtin_amdgcn_mfma_f32_16x16x32_bf16(a, bfr[6 + ks], acc3, 0, 0, 0);
        }

        // C/D: col(t-part)=lane&15, row(batch-in-group)=4*hi+reg. Direct stores;
        // the block's 4 waves cover a full 128B line per (batch,row) -> L2 merges
        // (WRITE_SIZE stayed ~66-68MB in rounds 5/7 with this pattern).
        f32x4 mk = *reinterpret_cast<const f32x4*>(&smask[w * 32 + bg * 16 + 4 * hi]);
        float* ob = out + (size_t)(bh * 32 + bg * 16 + 4 * hi) * HW * HW
                        + (size_t)(ph * 8 + (lo >> 3)) * HW + pq * 32 + w * 8 + (lo & 7);
        #pragma unroll
        for (int n = 0; n < 4; ++n) {
            f32x4 acc = (n == 0) ? acc0 : (n == 1) ? acc1 : (n == 2) ? acc2 : acc3;
            #pragma unroll
            for (int q2 = 0; q2 < 4; ++q2) {
                float val = fmaf(acc[q2], g, bi);
                val = (mk[q2] > 0.f) ? val : 0.f;
                ob[(size_t)q2 * HW * HW + (size_t)(2 * n) * HW] = val;
            }
        }
    }
}

extern "C" void kernel_launch(void* const* d_in, const int* in_sizes, int n_in,
                              void* d_out, int out_size, void* d_ws, size_t ws_size,
                              hipStream_t stream) {
    const float* src    = (const float*)d_in[0];
    const float* tr     = (const float*)d_in[1];
    const float* gates  = (const float*)d_in[2];
    const float* biases = (const float*)d_in[3];
    float* out = (float*)d_out;

    dim3 grid(2048);   // 8 blocks/CU x 256 CUs, zero tail
    dim3 block(256);   // 4 waves, wave = patch
    hipLaunchKernelGGL(axonal_kernel, grid, block, 0, stream,
                       src, tr, gates, biases, out);
}

// Round 9
// 40.210 us; speedup vs baseline: 1.0651x; 1.0084x over previous
//
#include <hip/hip_runtime.h>

#define HW 512
#define PSTRIDE 66    // shorts per patch slot in pbuf (33 dwords -> odd bank step)
#define BSTRIDE 266   // shorts per batch in pbuf (133 dwords -> odd bank step)

typedef __attribute__((ext_vector_type(4))) float f32x4;
typedef __attribute__((ext_vector_type(4))) int   i32x4;
typedef __attribute__((ext_vector_type(8))) short b16x8;
typedef __attribute__((ext_vector_type(4))) short b16x4;

__device__ __forceinline__ short f2bf(float f) {
    union { float f; unsigned u; } v; v.f = f;
    return (short)((v.u + 0x7FFFu + ((v.u >> 16) & 1u)) >> 16);  // RNE
}

__global__ __launch_bounds__(256, 4) void axonal_kernel(
    const float* __restrict__ src, const float* __restrict__ tr,
    const float* __restrict__ gates, const float* __restrict__ biases,
    float* __restrict__ out)
{
    // bh in bit 3: the two blocks sharing a patch-quad's transforms (bid, bid^8)
    // land on the same XCD -> their concurrent tr reads merge in that L2.
    const int bid = blockIdx.x;                    // 0..2047
    const int bh  = (bid >> 3) & 1;                // batch half
    const int q   = (bid >> 4) * 8 + (bid & 7);    // patch-quad 0..1023
    const int ph  = q >> 4;
    const int pq  = q & 15;                        // 4 adjacent pw = 128B line
    const int tid = threadIdx.x;
    const int w   = tid >> 6;                      // wave = patch within quad
    const int lane = tid & 63;
    const int lo  = lane & 15;
    const int hi  = lane >> 4;
    const int p   = (ph << 6) + (pq << 2) + w;

    __shared__ __align__(16) short pbuf[32 * BSTRIDE];  // [32 b][4 p][64+pad] bf16
    __shared__ float smask[4 * 32];                     // [patch][batch] strength

    // ---- B fragments (Tr[p]^T) into VGPRs, once.
    // mfma_f32_16x16x32_bf16: elems 0-3 <- k = ks*32 + 4*hi + j, elems 4-7 <- +16; col = lane&15.
    b16x8 bfr[8];  // [n*2 + ks]
    {
        const float* tp = tr + ((size_t)p << 12);
        #pragma unroll
        for (int n = 0; n < 4; ++n)
            #pragma unroll
            for (int ks = 0; ks < 2; ++ks) {
                const float* rp = tp + (n * 16 + lo) * 64 + ks * 32 + 4 * hi;
                float4 u0 = *reinterpret_cast<const float4*>(rp);
                float4 u1 = *reinterpret_cast<const float4*>(rp + 16);
                b16x8 v;
                v[0] = f2bf(u0.x); v[1] = f2bf(u0.y); v[2] = f2bf(u0.z); v[3] = f2bf(u0.w);
                v[4] = f2bf(u1.x); v[5] = f2bf(u1.y); v[6] = f2bf(u1.z); v[7] = f2bf(u1.w);
                bfr[n * 2 + ks] = v;
            }
    }
    // OPAQUE pin (round 8 fix): "+v" makes each fragment the OUTPUT of a volatile asm.
    // Uses must consume the asm's register; the tr-load+convert cannot be rematerialized
    // at the MFMA sites (input-only "v" pins only the materialization point, R5/R7/R8: VGPR 32-44).
    #pragma unroll
    for (int i = 0; i < 8; ++i) {
        i32x4 kv = (i32x4)bfr[i];
        asm volatile("" : "+v"(kv));
        bfr[i] = (b16x8)kv;
    }
    const float g  = gates[p];
    const float bi = biases[p];

    // ---- stage 32 batches: thread = (batch sb, col-quad u); 8 rows each.
    // Per wave-instr: 8 batches x 128B contiguous segments.
    {
        const int sb = tid >> 3;        // 0..31
        const int u  = tid & 7;         // col-quad; patch = u>>1
        const float* sp = src + (size_t)(bh * 32 + sb) * HW * HW
                              + (size_t)(ph * 8) * HW + pq * 32 + u * 4;
        short* dst = &pbuf[sb * BSTRIDE + (u >> 1) * PSTRIDE + (u & 1) * 4];
        float ssum = 0.f;
        #pragma unroll
        for (int r = 0; r < 8; ++r) {
            float4 v = *reinterpret_cast<const float4*>(sp + r * HW);
            ssum += (v.x + v.y) + (v.z + v.w);
            b16x4 bv;
            bv[0] = f2bf(v.x); bv[1] = f2bf(v.y); bv[2] = f2bf(v.z); bv[3] = f2bf(v.w);
            *reinterpret_cast<b16x4*>(dst + r * 8) = bv;
        }
        ssum += __shfl_xor(ssum, 1);    // partner col-quad of same patch
        if ((u & 1) == 0) smask[(u >> 1) * 32 + sb] = ssum;
    }
    __syncthreads();   // the only barrier

    // ---- 2 batch-groups of 16; per group: 4 ds_read_b64 + 8 MFMAs, direct stores.
    #pragma unroll
    for (int bg = 0; bg < 2; ++bg) {
        f32x4 acc0 = (f32x4){0.f, 0.f, 0.f, 0.f};
        f32x4 acc1 = acc0, acc2 = acc0, acc3 = acc0;
        #pragma unroll
        for (int ks = 0; ks < 2; ++ks) {
            const short* ap = &pbuf[(bg * 16 + lo) * BSTRIDE + w * PSTRIDE + ks * 32 + 4 * hi];
            b16x4 a0 = *reinterpret_cast<const b16x4*>(ap);
            b16x4 a1 = *reinterpret_cast<const b16x4*>(ap + 16);
            b16x8 a;
            a[0] = a0[0]; a[1] = a0[1]; a[2] = a0[2]; a[3] = a0[3];
            a[4] = a1[0]; a[5] = a1[1]; a[6] = a1[2]; a[7] = a1[3];
            acc0 = __builtin_amdgcn_mfma_f32_16x16x32_bf16(a, bfr[0 + ks], acc0, 0, 0, 0);
            acc1 = __builtin_amdgcn_mfma_f32_16x16x32_bf16(a, bfr[2 + ks], acc1, 0, 0, 0);
            acc2 = __builtin_amdgcn_mfma_f32_16x16x32_bf16(a, bfr[4 + ks], acc2, 0, 0, 0);
            acc3 = __builtin_amdgcn_mfma_f32_16x16x32_bf16(a, bfr[6 + ks], acc3, 0, 0, 0);
        }

        // C/D: col(t-part)=lane&15, row(batch-in-group)=4*hi+reg. Direct stores;
        // the block's 4 waves cover a full 128B line per (batch,row) -> L2 merges
        // (WRITE_SIZE stayed ~66-68MB in rounds 5/7/8 with this pattern).
        f32x4 mk = *reinterpret_cast<const f32x4*>(&smask[w * 32 + bg * 16 + 4 * hi]);
        float* ob = out + (size_t)(bh * 32 + bg * 16 + 4 * hi) * HW * HW
                        + (size_t)(ph * 8 + (lo >> 3)) * HW + pq * 32 + w * 8 + (lo & 7);
        #pragma unroll
        for (int n = 0; n < 4; ++n) {
            f32x4 acc = (n == 0) ? acc0 : (n == 1) ? acc1 : (n == 2) ? acc2 : acc3;
            #pragma unroll
            for (int q2 = 0; q2 < 4; ++q2) {
                float val = fmaf(acc[q2], g, bi);
                val = (mk[q2] > 0.f) ? val : 0.f;
                ob[(size_t)q2 * HW * HW + (size_t)(2 * n) * HW] = val;
            }
        }
    }
}

extern "C" void kernel_launch(void* const* d_in, const int* in_sizes, int n_in,
                              void* d_out, int out_size, void* d_ws, size_t ws_size,
                              hipStream_t stream) {
    const float* src    = (const float*)d_in[0];
    const float* tr     = (const float*)d_in[1];
    const float* gates  = (const float*)d_in[2];
    const float* biases = (const float*)d_in[3];
    float* out = (float*)d_out;

    dim3 grid(2048);   // 8 blocks/CU x 256 CUs, zero tail
    dim3 block(256);   // 4 waves, wave = patch
    hipLaunchKernelGGL(axonal_kernel, grid, block, 0, stream,
                       src, tr, gates, biases, out);
}